// Round 10
// baseline (172.229 us; speedup 1.0000x reference)
//
#include <hip/hip_runtime.h>

#define E_EDGES 3200000
#define N_NODES_K 100000
#define NEG_INF_F (-10000000000.0f)
#define KE_NB (E_EDGES / 256)   // 12500 blocks

typedef __attribute__((ext_vector_type(8))) short short8v;
typedef __attribute__((ext_vector_type(4))) float floatx4;

// round-to-nearest-even f32 -> bf16 pair packed into one uint (a low, b high)
__device__ __forceinline__ unsigned packbf2(float a, float b) {
    unsigned ua = __float_as_uint(a), ub = __float_as_uint(b);
    ua = (ua + 0x7fffu + ((ua >> 16) & 1u)) >> 16;
    ub = (ub + 0x7fffu + ((ub >> 16) & 1u)) & 0xffff0000u;
    return ub | ua;
}

// ---------------------------------------------------------------------------
// KP: node projections (packed bf16 pairs) + fused dtype detection.
//   P1c[n][j] = packbf2(p1[j], p1[j+16])  (p1 = nr@W1[0:32]+b1), row = 64 B
//   P2c likewise for W1[32:64], no bias.
//   flags[0]: edge_index int64(1)/int32(0); flags[1]: sel int32/byte/float
// ---------------------------------------------------------------------------
__global__ __launch_bounds__(256) void k_nodeproj(
    const float* __restrict__ nr, const float* __restrict__ W1,
    const float* __restrict__ b1, unsigned* __restrict__ P1c,
    unsigned* __restrict__ P2c, const unsigned* __restrict__ ei_w,
    const unsigned* __restrict__ sel_w, int* __restrict__ flags) {
    if (blockIdx.x == 0 && threadIdx.x < 64) {
        const int lane = threadIdx.x;
        unsigned hw = ei_w[2 * (lane + 1) + 1];  // hi-word if int64 (ids < 2^17)
        unsigned long long anyhi = __ballot(hw != 0u);
        unsigned sv = sel_w[lane];
        unsigned long long not01 = __ballot(sv != 0u && sv != 1u);
        unsigned long long notf  = __ballot(sv != 0u && sv != 0x3F800000u);
        if (lane == 0) {
            flags[0] = (anyhi == 0ull) ? 1 : 0;
            flags[1] = (not01 == 0ull) ? 0 : ((notf == 0ull) ? 2 : 1);
        }
    }
    int n = blockIdx.x * 256 + threadIdx.x;
    if (n >= N_NODES_K) return;
    const float4* x4 = (const float4*)(nr + (size_t)n * 32);
    float xr[32];
#pragma unroll
    for (int i = 0; i < 8; ++i) {
        float4 t = x4[i];
        xr[4 * i + 0] = t.x; xr[4 * i + 1] = t.y; xr[4 * i + 2] = t.z; xr[4 * i + 3] = t.w;
    }
    float a1[32], a2[32];
#pragma unroll
    for (int j = 0; j < 32; ++j) { a1[j] = b1[j]; a2[j] = 0.0f; }
#pragma unroll
    for (int k = 0; k < 32; ++k) {
        const float xv = xr[k];
#pragma unroll
        for (int jb = 0; jb < 8; ++jb) {
            const float4 w1 = *(const float4*)(W1 + (size_t)k * 32 + jb * 4);
            const float4 w2 = *(const float4*)(W1 + (size_t)(32 + k) * 32 + jb * 4);
            a1[4 * jb + 0] = fmaf(xv, w1.x, a1[4 * jb + 0]);
            a1[4 * jb + 1] = fmaf(xv, w1.y, a1[4 * jb + 1]);
            a1[4 * jb + 2] = fmaf(xv, w1.z, a1[4 * jb + 2]);
            a1[4 * jb + 3] = fmaf(xv, w1.w, a1[4 * jb + 3]);
            a2[4 * jb + 0] = fmaf(xv, w2.x, a2[4 * jb + 0]);
            a2[4 * jb + 1] = fmaf(xv, w2.y, a2[4 * jb + 1]);
            a2[4 * jb + 2] = fmaf(xv, w2.z, a2[4 * jb + 2]);
            a2[4 * jb + 3] = fmaf(xv, w2.w, a2[4 * jb + 3]);
        }
    }
    unsigned r1[16], r2[16];
#pragma unroll
    for (int j = 0; j < 16; ++j) {
        r1[j] = packbf2(a1[j], a1[j + 16]);
        r2[j] = packbf2(a2[j], a2[j + 16]);
    }
    uint4* o1 = (uint4*)(P1c + (size_t)n * 16);
    uint4* o2 = (uint4*)(P2c + (size_t)n * 16);
#pragma unroll
    for (int i = 0; i < 4; ++i) {
        o1[i] = ((const uint4*)r1)[i];
        o2[i] = ((const uint4*)r2)[i];
    }
}

// ---------------------------------------------------------------------------
// KE (MFMA, predicated, software-pipelined): R8 structure, but ALL gated
// loads (er + P-gathers for all 4 t-iterations) are issued up front in one
// exec-masked pass so their latencies overlap; compute consumes afterwards.
// ---------------------------------------------------------------------------
__global__ __launch_bounds__(256) void k_edge(
    const float* __restrict__ er_, const float* __restrict__ W1,
    const float* __restrict__ gr, const float* __restrict__ sgr,
    const void* __restrict__ ei_raw, const void* __restrict__ sel_raw,
    const int* __restrict__ flags,
    const unsigned* __restrict__ P1c, const unsigned* __restrict__ P2c,
    float* __restrict__ scores, float* __restrict__ bmax,
    float* __restrict__ bsum) {
    __shared__ int sIdx[256];
    __shared__ int dIdx[256];
    __shared__ int aAct[256];
    __shared__ float sred[8];

    const int tid = threadIdx.x;
    const int e0 = blockIdx.x * 256;
    const int fei = flags[0], fsel = flags[1];

    bool act;
    if (fsel == 0)
        act = __builtin_nontemporal_load((const int*)sel_raw + e0 + tid) == 0;
    else if (fsel == 1)
        act = __builtin_nontemporal_load((const unsigned char*)sel_raw + e0 + tid) == 0;
    else
        act = __builtin_nontemporal_load((const float*)sel_raw + e0 + tid) == 0.0f;

    int s = 0, d = 0;
    if (act) {
        if (fei) {
            s = __builtin_nontemporal_load((const int*)ei_raw + 2 * (size_t)(e0 + tid));
            d = __builtin_nontemporal_load((const int*)ei_raw +
                                           2 * ((size_t)E_EDGES + e0 + tid));
        } else {
            s = __builtin_nontemporal_load((const int*)ei_raw + e0 + tid);
            d = __builtin_nontemporal_load((const int*)ei_raw + E_EDGES + e0 + tid);
        }
    }
    sIdx[tid] = s; dIdx[tid] = d; aAct[tid] = act ? 1 : 0;

    const int lane = tid & 63;
    const int wv   = tid >> 6;     // wave 0..3
    const int col  = lane & 15;    // edge-in-tile (B/C col); j-row for A build
    const int g    = lane >> 4;    // k-group
    const int kb   = g * 8;

    // A-frags (W3^T), built once: elem i = W3[kb+i][row]; row = col / 16+col
    union { unsigned u[4]; short8v v; } A0, A1;
#pragma unroll
    for (int t = 0; t < 4; ++t) {
        float x0 = W1[(size_t)(64 + kb + 2 * t) * 32 + col];
        float x1 = W1[(size_t)(64 + kb + 2 * t + 1) * 32 + col];
        A0.u[t] = packbf2(x0, x1);
        float y0 = W1[(size_t)(64 + kb + 2 * t) * 32 + 16 + col];
        float y1 = W1[(size_t)(64 + kb + 2 * t + 1) * 32 + 16 + col];
        A1.u[t] = packbf2(y0, y1);
    }
    // gdiff for this lane's j's: j = g*4+r (acc0) and 16+g*4+r (acc1)
    float gd0[4], gd1[4];
#pragma unroll
    for (int r = 0; r < 4; ++r) {
        gd0[r] = gr[g * 4 + r] - sgr[g * 4 + r];
        gd1[r] = gr[16 + g * 4 + r] - sgr[16 + g * 4 + r];
    }
    __syncthreads();   // staged indices ready

    // per-t indices from LDS
    int se[4], de[4], ea[4];
#pragma unroll
    for (int t = 0; t < 4; ++t) {
        const int erow = (wv * 4 + t) * 16 + col;
        se[t] = sIdx[erow]; de[t] = dIdx[erow]; ea[t] = aAct[erow];
    }

    // ---- issue ALL gated loads up front (latencies overlap) ----
    floatx4 xa[4], xb[4];
    uint4 u1[4], u2[4];
#pragma unroll
    for (int t = 0; t < 4; ++t) {
        xa[t] = (floatx4){0.f, 0.f, 0.f, 0.f};
        xb[t] = (floatx4){0.f, 0.f, 0.f, 0.f};
        u1[t] = make_uint4(0u, 0u, 0u, 0u);
        u2[t] = make_uint4(0u, 0u, 0u, 0u);
        if (ea[t]) {
            const int erow = (wv * 4 + t) * 16 + col;
            const floatx4* ep = (const floatx4*)(er_ + (size_t)(e0 + erow) * 32 + kb);
            xa[t] = __builtin_nontemporal_load(ep);
            xb[t] = __builtin_nontemporal_load(ep + 1);
            u1[t] = *(const uint4*)(P1c + (size_t)se[t] * 16 + g * 4);
            u2[t] = *(const uint4*)(P2c + (size_t)de[t] * 16 + g * 4);
        }
    }

    // ---- compute stages consume in issue order ----
    float s_loc[4];
#pragma unroll
    for (int t = 0; t < 4; ++t) {
        const int erow = (wv * 4 + t) * 16 + col;
        union { unsigned u[4]; short8v v; } B;
        B.u[0] = packbf2(xa[t].x, xa[t].y); B.u[1] = packbf2(xa[t].z, xa[t].w);
        B.u[2] = packbf2(xb[t].x, xb[t].y); B.u[3] = packbf2(xb[t].z, xb[t].w);

        floatx4 acc0 = {0.f, 0.f, 0.f, 0.f}, acc1 = {0.f, 0.f, 0.f, 0.f};
        acc0 = __builtin_amdgcn_mfma_f32_16x16x32_bf16(A0.v, B.v, acc0, 0, 0, 0);
        acc1 = __builtin_amdgcn_mfma_f32_16x16x32_bf16(A1.v, B.v, acc1, 0, 0, 0);

        const unsigned* pu1 = (const unsigned*)&u1[t];
        const unsigned* pu2 = (const unsigned*)&u2[t];
        float part = 0.0f;
#pragma unroll
        for (int r = 0; r < 4; ++r) {
            float z0 = acc0[r] + __uint_as_float(pu1[r] << 16)
                               + __uint_as_float(pu2[r] << 16);
            float z1 = acc1[r] + __uint_as_float(pu1[r] & 0xffff0000u)
                               + __uint_as_float(pu2[r] & 0xffff0000u);
            float h0 = z0 > 0.0f ? z0 : (__expf(z0) - 1.0f);
            float h1 = z1 > 0.0f ? z1 : (__expf(z1) - 1.0f);
            part = fmaf(h0, gd0[r], part);
            part = fmaf(h1, gd1[r], part);
        }
        // sum the 4 k-groups (lanes col, col+16, col+32, col+48)
        part += __shfl_xor(part, 16);
        part += __shfl_xor(part, 32);
        float sc = ea[t] ? part : NEG_INF_F;
        s_loc[t] = sc;
        if (g == 0) __builtin_nontemporal_store(sc, scores + e0 + erow);
    }

    // block max
    float m = fmaxf(fmaxf(s_loc[0], s_loc[1]), fmaxf(s_loc[2], s_loc[3]));
#pragma unroll
    for (int off = 32; off > 0; off >>= 1) m = fmaxf(m, __shfl_down(m, off));
    if (lane == 0) sred[wv] = m;
    __syncthreads();
    const float mb = fmaxf(fmaxf(sred[0], sred[1]), fmaxf(sred[2], sred[3]));
    // block sumexp (g==0 lanes only — values are 4x replicated across groups)
    float v = 0.0f;
    if (g == 0) {
#pragma unroll
        for (int t = 0; t < 4; ++t) v += __expf((s_loc[t] - mb) * 2.0f);
    }
#pragma unroll
    for (int off = 32; off > 0; off >>= 1) v += __shfl_down(v, off);
    __syncthreads();
    if (lane == 0) sred[4 + wv] = v;
    __syncthreads();
    if (tid == 0) {
        bmax[blockIdx.x] = mb;
        bsum[blockIdx.x] = sred[4] + sred[5] + sred[6] + sred[7];
    }
}

// ---------------------------------------------------------------------------
// KR: one block — global max + rescaled sum over block partials
// ---------------------------------------------------------------------------
__global__ __launch_bounds__(256) void k_reduce(
    const float* __restrict__ bmax, const float* __restrict__ bsum,
    float* __restrict__ mx_out, float* __restrict__ rsum_out) {
    const int tid = threadIdx.x;
    __shared__ float sm[4];
    float m = -3.0e38f;
    for (int i = tid; i < KE_NB; i += 256) m = fmaxf(m, bmax[i]);
#pragma unroll
    for (int off = 32; off > 0; off >>= 1) m = fmaxf(m, __shfl_down(m, off));
    const int lane = tid & 63, wid = tid >> 6;
    if (lane == 0) sm[wid] = m;
    __syncthreads();
    const float M = fmaxf(fmaxf(sm[0], sm[1]), fmaxf(sm[2], sm[3]));
    float s = 0.0f;
    for (int i = tid; i < KE_NB; i += 256)
        s += bsum[i] * __expf((bmax[i] - M) * 2.0f);
#pragma unroll
    for (int off = 32; off > 0; off >>= 1) s += __shfl_down(s, off);
    __syncthreads();
    __shared__ float ss[4];
    if (lane == 0) ss[wid] = s;
    __syncthreads();
    if (tid == 0) {
        *mx_out = M;
        *rsum_out = 1.0f / (ss[0] + ss[1] + ss[2] + ss[3]);
    }
}

// ---------------------------------------------------------------------------
// KF: out = exp((score - M)/T) * rsum
// ---------------------------------------------------------------------------
__global__ __launch_bounds__(256) void k_fin(
    const float* __restrict__ scores, const float* __restrict__ mx,
    const float* __restrict__ rsum, float* __restrict__ out) {
    const int i = blockIdx.x * 256 + threadIdx.x;
    const float M = *mx;
    const float r = *rsum;
    float4 s = ((const float4*)scores)[i];
    float4 o;
    o.x = __expf((s.x - M) * 2.0f) * r;
    o.y = __expf((s.y - M) * 2.0f) * r;
    o.z = __expf((s.z - M) * 2.0f) * r;
    o.w = __expf((s.w - M) * 2.0f) * r;
    ((float4*)out)[i] = o;
}

extern "C" void kernel_launch(void* const* d_in, const int* in_sizes, int n_in,
                              void* d_out, int out_size, void* d_ws, size_t ws_size,
                              hipStream_t stream) {
    const float* node_reps    = (const float*)d_in[0];
    const float* edge_reps    = (const float*)d_in[1];
    const float* graph_rep    = (const float*)d_in[2];
    const float* subgraph_rep = (const float*)d_in[3];
    const float* W1           = (const float*)d_in[4];
    const float* b1           = (const float*)d_in[5];
    const void*  ei           = d_in[6];
    const void*  selp         = d_in[7];
    float* out = (float*)d_out;

    char* ws = (char*)d_ws;
    size_t off = 0;
    unsigned* P1c = (unsigned*)(ws + off); off += (size_t)N_NODES_K * 64;   // 6.4 MB
    unsigned* P2c = (unsigned*)(ws + off); off += (size_t)N_NODES_K * 64;   // 6.4 MB
    float* scores = (float*)(ws + off);    off += (size_t)E_EDGES * 4;      // 12.8 MB
    float* bmax   = (float*)(ws + off);    off += (size_t)KE_NB * 4;
    float* bsum   = (float*)(ws + off);    off += (size_t)KE_NB * 4;
    int*   flags  = (int*)(ws + off);      off += 64;
    float* mx     = (float*)(ws + off);    off += 4;
    float* rsum   = (float*)(ws + off);    off += 4;

    k_nodeproj<<<(N_NODES_K + 255) / 256, 256, 0, stream>>>(
        node_reps, W1, b1, P1c, P2c,
        (const unsigned*)ei, (const unsigned*)selp, flags);
    k_edge<<<KE_NB, 256, 0, stream>>>(edge_reps, W1, graph_rep, subgraph_rep,
                                      ei, selp, flags, P1c, P2c, scores, bmax, bsum);
    k_reduce<<<1, 256, 0, stream>>>(bmax, bsum, mx, rsum);
    k_fin<<<E_EDGES / 4 / 256, 256, 0, stream>>>(scores, mx, rsum, out);
}

// Round 11
// 113.577 us; speedup vs baseline: 1.5164x; 1.5164x over previous
//
#include <hip/hip_runtime.h>

#define E_EDGES 3200000
#define N_NODES_K 100000
#define NEG_INF_F (-10000000000.0f)
#define KE_NB (E_EDGES / 256)          // 12500 blocks
#define NP_NB ((N_NODES_K + 63) / 64)  // 1563 blocks

typedef __attribute__((ext_vector_type(8))) short short8v;
typedef __attribute__((ext_vector_type(4))) float floatx4;

// round-to-nearest-even f32 -> bf16 pair packed into one uint (a low, b high)
__device__ __forceinline__ unsigned packbf2(float a, float b) {
    unsigned ua = __float_as_uint(a), ub = __float_as_uint(b);
    ua = (ua + 0x7fffu + ((ua >> 16) & 1u)) >> 16;
    ub = (ub + 0x7fffu + ((ub >> 16) & 1u)) & 0xffff0000u;
    return ub | ua;
}

// ---------------------------------------------------------------------------
// KP (MFMA): P1/P2 node projections. Per wave: 16 nodes, 4 MFMAs (K=32).
//   A-frag: lane(col,g) holds nr[n0+col][g*8..g*8+7]  (row=col per m89 A-layout)
//   B-frag: lane(col,g) holds W1[g*8..g*8+7][col(+16)] (col=lane&15)
//   D: lane(col,g) reg r -> D[node=g*4+r][j=col]; pack (j, j+16) -> one uint.
// Fused dtype detection on block 0 / wave 0.
// ---------------------------------------------------------------------------
__global__ __launch_bounds__(256) void k_nodeproj(
    const float* __restrict__ nr, const float* __restrict__ W1,
    const float* __restrict__ b1, unsigned* __restrict__ P1c,
    unsigned* __restrict__ P2c, const unsigned* __restrict__ ei_w,
    const unsigned* __restrict__ sel_w, int* __restrict__ flags) {
    if (blockIdx.x == 0 && threadIdx.x < 64) {
        const int lane = threadIdx.x;
        unsigned hw = ei_w[2 * (lane + 1) + 1];  // hi-word if int64 (ids < 2^17)
        unsigned long long anyhi = __ballot(hw != 0u);
        unsigned sv = sel_w[lane];
        unsigned long long not01 = __ballot(sv != 0u && sv != 1u);
        unsigned long long notf  = __ballot(sv != 0u && sv != 0x3F800000u);
        if (lane == 0) {
            flags[0] = (anyhi == 0ull) ? 1 : 0;
            flags[1] = (not01 == 0ull) ? 0 : ((notf == 0ull) ? 2 : 1);
        }
    }
    const int tid  = threadIdx.x;
    const int lane = tid & 63;
    const int wv   = tid >> 6;
    const int col  = lane & 15;
    const int g    = lane >> 4;
    const int kb   = g * 8;
    const int n0   = blockIdx.x * 64 + wv * 16;

    // A-frag: nr row (clamped for tail; stores predicated below)
    int nrow = n0 + col;
    if (nrow >= N_NODES_K) nrow = N_NODES_K - 1;
    const float4* ap = (const float4*)(nr + (size_t)nrow * 32 + kb);
    float4 av0 = ap[0], av1 = ap[1];
    union { unsigned u[4]; short8v v; } A;
    A.u[0] = packbf2(av0.x, av0.y); A.u[1] = packbf2(av0.z, av0.w);
    A.u[2] = packbf2(av1.x, av1.y); A.u[3] = packbf2(av1.z, av1.w);

    // B-frags: W1 block rows kb..kb+7, cols col / 16+col (wave-uniform rows)
    union { unsigned u[4]; short8v v; } B1lo, B1hi, B2lo, B2hi;
#pragma unroll
    for (int t = 0; t < 4; ++t) {
        const size_t r0 = (size_t)(kb + 2 * t) * 32, r1 = r0 + 32;
        B1lo.u[t] = packbf2(W1[r0 + col],          W1[r1 + col]);
        B1hi.u[t] = packbf2(W1[r0 + 16 + col],     W1[r1 + 16 + col]);
        const size_t s0 = (size_t)(32 + kb + 2 * t) * 32, s1 = s0 + 32;
        B2lo.u[t] = packbf2(W1[s0 + col],          W1[s1 + col]);
        B2hi.u[t] = packbf2(W1[s0 + 16 + col],     W1[s1 + 16 + col]);
    }
    const float blo = b1[col], bhi = b1[16 + col];

    floatx4 a1lo = {0.f,0.f,0.f,0.f}, a1hi = {0.f,0.f,0.f,0.f};
    floatx4 a2lo = {0.f,0.f,0.f,0.f}, a2hi = {0.f,0.f,0.f,0.f};
    a1lo = __builtin_amdgcn_mfma_f32_16x16x32_bf16(A.v, B1lo.v, a1lo, 0, 0, 0);
    a1hi = __builtin_amdgcn_mfma_f32_16x16x32_bf16(A.v, B1hi.v, a1hi, 0, 0, 0);
    a2lo = __builtin_amdgcn_mfma_f32_16x16x32_bf16(A.v, B2lo.v, a2lo, 0, 0, 0);
    a2hi = __builtin_amdgcn_mfma_f32_16x16x32_bf16(A.v, B2hi.v, a2hi, 0, 0, 0);

#pragma unroll
    for (int r = 0; r < 4; ++r) {
        const int n = n0 + g * 4 + r;
        if (n < N_NODES_K) {
            P1c[(size_t)n * 16 + col] = packbf2(a1lo[r] + blo, a1hi[r] + bhi);
            P2c[(size_t)n * 16 + col] = packbf2(a2lo[r], a2hi[r]);
        }
    }
}

// ---------------------------------------------------------------------------
// KE (MFMA, predicated — R8 structure): per block 256 edges. er + P loads
// predicated on act (exec-masked skip); er/sel/ei nontemporal; P-gather
// issued alongside er load (before MFMA) to shorten exposed latency.
// ---------------------------------------------------------------------------
__global__ __launch_bounds__(256) void k_edge(
    const float* __restrict__ er_, const float* __restrict__ W1,
    const float* __restrict__ gr, const float* __restrict__ sgr,
    const void* __restrict__ ei_raw, const void* __restrict__ sel_raw,
    const int* __restrict__ flags,
    const unsigned* __restrict__ P1c, const unsigned* __restrict__ P2c,
    float* __restrict__ scores, float* __restrict__ bmax,
    float* __restrict__ bsum) {
    __shared__ int sIdx[256];
    __shared__ int dIdx[256];
    __shared__ int aAct[256];
    __shared__ float sred[8];

    const int tid = threadIdx.x;
    const int e0 = blockIdx.x * 256;
    const int fei = flags[0], fsel = flags[1];

    bool act;
    if (fsel == 0)
        act = __builtin_nontemporal_load((const int*)sel_raw + e0 + tid) == 0;
    else if (fsel == 1)
        act = __builtin_nontemporal_load((const unsigned char*)sel_raw + e0 + tid) == 0;
    else
        act = __builtin_nontemporal_load((const float*)sel_raw + e0 + tid) == 0.0f;

    int s = 0, d = 0;
    if (act) {
        if (fei) {
            s = __builtin_nontemporal_load((const int*)ei_raw + 2 * (size_t)(e0 + tid));
            d = __builtin_nontemporal_load((const int*)ei_raw +
                                           2 * ((size_t)E_EDGES + e0 + tid));
        } else {
            s = __builtin_nontemporal_load((const int*)ei_raw + e0 + tid);
            d = __builtin_nontemporal_load((const int*)ei_raw + E_EDGES + e0 + tid);
        }
    }
    sIdx[tid] = s; dIdx[tid] = d; aAct[tid] = act ? 1 : 0;

    const int lane = tid & 63;
    const int wv   = tid >> 6;     // wave 0..3
    const int col  = lane & 15;    // edge-in-tile (B/C col); j-row for A build
    const int g    = lane >> 4;    // k-group
    const int kb   = g * 8;

    // A-frags (W3^T), built once: elem i = W3[kb+i][row]; row = col / 16+col
    union { unsigned u[4]; short8v v; } A0, A1;
#pragma unroll
    for (int t = 0; t < 4; ++t) {
        float x0 = W1[(size_t)(64 + kb + 2 * t) * 32 + col];
        float x1 = W1[(size_t)(64 + kb + 2 * t + 1) * 32 + col];
        A0.u[t] = packbf2(x0, x1);
        float y0 = W1[(size_t)(64 + kb + 2 * t) * 32 + 16 + col];
        float y1 = W1[(size_t)(64 + kb + 2 * t + 1) * 32 + 16 + col];
        A1.u[t] = packbf2(y0, y1);
    }
    // gdiff for this lane's j's: j = g*4+r (acc0) and 16+g*4+r (acc1)
    float gd0[4], gd1[4];
#pragma unroll
    for (int r = 0; r < 4; ++r) {
        gd0[r] = gr[g * 4 + r] - sgr[g * 4 + r];
        gd1[r] = gr[16 + g * 4 + r] - sgr[16 + g * 4 + r];
    }
    __syncthreads();   // staged indices ready

    float s_loc[4];
#pragma unroll
    for (int t = 0; t < 4; ++t) {
        const int erow = (wv * 4 + t) * 16 + col;   // edge within block
        const bool ea = aAct[erow] != 0;

        // issue er load AND P-gathers together (both exec-mask-skipped when
        // masked); MFMA depends only on er, epilogue on the gathers.
        union { unsigned u[4]; short8v v; } B;
        B.u[0] = 0u; B.u[1] = 0u; B.u[2] = 0u; B.u[3] = 0u;
        uint4 u1 = make_uint4(0u, 0u, 0u, 0u), u2 = make_uint4(0u, 0u, 0u, 0u);
        if (ea) {
            const floatx4* ep = (const floatx4*)(er_ + (size_t)(e0 + erow) * 32 + kb);
            floatx4 xa = __builtin_nontemporal_load(ep);
            floatx4 xb = __builtin_nontemporal_load(ep + 1);
            u1 = *(const uint4*)(P1c + (size_t)sIdx[erow] * 16 + g * 4);
            u2 = *(const uint4*)(P2c + (size_t)dIdx[erow] * 16 + g * 4);
            B.u[0] = packbf2(xa.x, xa.y); B.u[1] = packbf2(xa.z, xa.w);
            B.u[2] = packbf2(xb.x, xb.y); B.u[3] = packbf2(xb.z, xb.w);
        }

        floatx4 acc0 = {0.f, 0.f, 0.f, 0.f}, acc1 = {0.f, 0.f, 0.f, 0.f};
        acc0 = __builtin_amdgcn_mfma_f32_16x16x32_bf16(A0.v, B.v, acc0, 0, 0, 0);
        acc1 = __builtin_amdgcn_mfma_f32_16x16x32_bf16(A1.v, B.v, acc1, 0, 0, 0);

        const unsigned* pu1 = (const unsigned*)&u1;
        const unsigned* pu2 = (const unsigned*)&u2;
        float part = 0.0f;
#pragma unroll
        for (int r = 0; r < 4; ++r) {
            float z0 = acc0[r] + __uint_as_float(pu1[r] << 16)
                               + __uint_as_float(pu2[r] << 16);
            float z1 = acc1[r] + __uint_as_float(pu1[r] & 0xffff0000u)
                               + __uint_as_float(pu2[r] & 0xffff0000u);
            float h0 = z0 > 0.0f ? z0 : (__expf(z0) - 1.0f);
            float h1 = z1 > 0.0f ? z1 : (__expf(z1) - 1.0f);
            part = fmaf(h0, gd0[r], part);
            part = fmaf(h1, gd1[r], part);
        }
        // sum the 4 k-groups (lanes col, col+16, col+32, col+48)
        part += __shfl_xor(part, 16);
        part += __shfl_xor(part, 32);
        float sc = ea ? part : NEG_INF_F;
        s_loc[t] = sc;
        if (g == 0) __builtin_nontemporal_store(sc, scores + e0 + erow);
    }

    // block max
    float m = fmaxf(fmaxf(s_loc[0], s_loc[1]), fmaxf(s_loc[2], s_loc[3]));
#pragma unroll
    for (int off = 32; off > 0; off >>= 1) m = fmaxf(m, __shfl_down(m, off));
    if (lane == 0) sred[wv] = m;
    __syncthreads();
    const float mb = fmaxf(fmaxf(sred[0], sred[1]), fmaxf(sred[2], sred[3]));
    // block sumexp (g==0 lanes only — values are 4x replicated across groups)
    float v = 0.0f;
    if (g == 0) {
#pragma unroll
        for (int t = 0; t < 4; ++t) v += __expf((s_loc[t] - mb) * 2.0f);
    }
#pragma unroll
    for (int off = 32; off > 0; off >>= 1) v += __shfl_down(v, off);
    __syncthreads();
    if (lane == 0) sred[4 + wv] = v;
    __syncthreads();
    if (tid == 0) {
        bmax[blockIdx.x] = mb;
        bsum[blockIdx.x] = sred[4] + sred[5] + sred[6] + sred[7];
    }
}

// ---------------------------------------------------------------------------
// KR: one 1024-thread block — global max + rescaled sum over 12500 partials
// ---------------------------------------------------------------------------
__global__ __launch_bounds__(1024) void k_reduce(
    const float* __restrict__ bmax, const float* __restrict__ bsum,
    float* __restrict__ mx_out, float* __restrict__ rsum_out) {
    const int tid = threadIdx.x;
    float m = -3.0e38f;
    for (int i = tid; i < KE_NB; i += 1024) m = fmaxf(m, bmax[i]);
#pragma unroll
    for (int off = 32; off > 0; off >>= 1) m = fmaxf(m, __shfl_down(m, off));
    __shared__ float sm[16];
    __shared__ float ss[16];
    const int lane = tid & 63, wid = tid >> 6;
    if (lane == 0) sm[wid] = m;
    __syncthreads();
    float M = -3.0e38f;
#pragma unroll
    for (int i = 0; i < 16; ++i) M = fmaxf(M, sm[i]);
    float sum = 0.0f;
    for (int i = tid; i < KE_NB; i += 1024)
        sum += bsum[i] * __expf((bmax[i] - M) * 2.0f);
#pragma unroll
    for (int off = 32; off > 0; off >>= 1) sum += __shfl_down(sum, off);
    if (lane == 0) ss[wid] = sum;
    __syncthreads();
    if (tid == 0) {
        float tot = 0.0f;
#pragma unroll
        for (int i = 0; i < 16; ++i) tot += ss[i];
        *mx_out = M;
        *rsum_out = 1.0f / tot;
    }
}

// ---------------------------------------------------------------------------
// KF: out = exp((score - M)/T) * rsum
// ---------------------------------------------------------------------------
__global__ __launch_bounds__(256) void k_fin(
    const float* __restrict__ scores, const float* __restrict__ mx,
    const float* __restrict__ rsum, float* __restrict__ out) {
    const int i = blockIdx.x * 256 + threadIdx.x;
    const float M = *mx;
    const float r = *rsum;
    float4 s = ((const float4*)scores)[i];
    float4 o;
    o.x = __expf((s.x - M) * 2.0f) * r;
    o.y = __expf((s.y - M) * 2.0f) * r;
    o.z = __expf((s.z - M) * 2.0f) * r;
    o.w = __expf((s.w - M) * 2.0f) * r;
    ((float4*)out)[i] = o;
}

extern "C" void kernel_launch(void* const* d_in, const int* in_sizes, int n_in,
                              void* d_out, int out_size, void* d_ws, size_t ws_size,
                              hipStream_t stream) {
    const float* node_reps    = (const float*)d_in[0];
    const float* edge_reps    = (const float*)d_in[1];
    const float* graph_rep    = (const float*)d_in[2];
    const float* subgraph_rep = (const float*)d_in[3];
    const float* W1           = (const float*)d_in[4];
    const float* b1           = (const float*)d_in[5];
    const void*  ei           = d_in[6];
    const void*  selp         = d_in[7];
    float* out = (float*)d_out;

    char* ws = (char*)d_ws;
    size_t off = 0;
    unsigned* P1c = (unsigned*)(ws + off); off += (size_t)N_NODES_K * 64;   // 6.4 MB
    unsigned* P2c = (unsigned*)(ws + off); off += (size_t)N_NODES_K * 64;   // 6.4 MB
    float* scores = (float*)(ws + off);    off += (size_t)E_EDGES * 4;      // 12.8 MB
    float* bmax   = (float*)(ws + off);    off += (size_t)KE_NB * 4;
    float* bsum   = (float*)(ws + off);    off += (size_t)KE_NB * 4;
    int*   flags  = (int*)(ws + off);      off += 64;
    float* mx     = (float*)(ws + off);    off += 4;
    float* rsum   = (float*)(ws + off);    off += 4;

    k_nodeproj<<<NP_NB, 256, 0, stream>>>(
        node_reps, W1, b1, P1c, P2c,
        (const unsigned*)ei, (const unsigned*)selp, flags);
    k_edge<<<KE_NB, 256, 0, stream>>>(edge_reps, W1, graph_rep, subgraph_rep,
                                      ei, selp, flags, P1c, P2c, scores, bmax, bsum);
    k_reduce<<<1, 1024, 0, stream>>>(bmax, bsum, mx, rsum);
    k_fin<<<E_EDGES / 4 / 256, 256, 0, stream>>>(scores, mx, rsum, out);
}